// Round 1
// baseline (1220.659 us; speedup 1.0000x reference)
//
#include <hip/hip_runtime.h>

#define N_NODES 50000
#define F 128

// ---- degree count: deg[dst] += 1 over the 800K real edges ----
__global__ void k_count(const int* __restrict__ dst, int E, float* __restrict__ deg) {
    int i = blockIdx.x * blockDim.x + threadIdx.x;
    if (i < E) atomicAdd(&deg[dst[i]], 1.0f);
}

// ---- dinv[i] = rsqrt(deg[i] + 1)  (+1 = self loop) ----
__global__ void k_rsqrt(float* __restrict__ deg, int n) {
    int i = blockIdx.x * blockDim.x + threadIdx.x;
    if (i < n) deg[i] = rsqrtf(deg[i] + 1.0f);
}

// ---- H = X @ W   (X: nrows x 128, W: 128 x 128, all fp32) ----
// W staged fully in LDS (64 KB). One wave per row; lane f computes cols f and f+64.
// Row broadcast via __shfl from two per-lane registers.
__global__ __launch_bounds__(256) void k_gemm(const float* __restrict__ X,
                                              const float* __restrict__ W,
                                              float* __restrict__ H, int nrows) {
    __shared__ float Ws[F * F];
    for (int i = threadIdx.x; i < F * F; i += 256) Ws[i] = W[i];
    __syncthreads();
    const int wid  = threadIdx.x >> 6;
    const int lane = threadIdx.x & 63;
    const int gw   = blockIdx.x * 4 + wid;
    const int nw   = gridDim.x * 4;
    for (int row = gw; row < nrows; row += nw) {
        const float x0 = X[row * F + lane];
        const float x1 = X[row * F + 64 + lane];
        float acc0 = 0.f, acc1 = 0.f;
#pragma unroll
        for (int k = 0; k < 64; ++k) {
            const float xv = __shfl(x0, k);
            acc0 += xv * Ws[k * F + lane];
            acc1 += xv * Ws[k * F + 64 + lane];
        }
#pragma unroll
        for (int k = 0; k < 64; ++k) {
            const float xv = __shfl(x1, k);
            acc0 += xv * Ws[(64 + k) * F + lane];
            acc1 += xv * Ws[(64 + k) * F + 64 + lane];
        }
        H[row * F + lane]      = acc0;
        H[row * F + 64 + lane] = acc1;
    }
}

// ---- out[i][f] = b[f] + dinv[i]^2 * H[i][f]   (bias + self-loop message) ----
__global__ void k_init(const float* __restrict__ H, const float* __restrict__ b,
                       const float* __restrict__ dinv, float* __restrict__ out, int n) {
    int i = blockIdx.x * blockDim.x + threadIdx.x;
    if (i < n * F) {
        const int row = i >> 7;
        const int f   = i & 127;
        const float d = dinv[row];
        out[i] = b[f] + d * d * H[i];
    }
}

// ---- edge-parallel scatter: one wave per edge, lane handles f and f+64 ----
__global__ __launch_bounds__(256) void k_scatter(const int* __restrict__ src,
                                                 const int* __restrict__ dst, int E,
                                                 const float* __restrict__ dinv,
                                                 const float* __restrict__ H,
                                                 float* __restrict__ out) {
    const int wid  = (blockIdx.x * blockDim.x + threadIdx.x) >> 6;
    const int lane = threadIdx.x & 63;
    const int nw   = (gridDim.x * blockDim.x) >> 6;
    for (int e = wid; e < E; e += nw) {
        const int s = src[e];
        const int d = dst[e];
        const float nrm = dinv[s] * dinv[d];
        atomicAdd(&out[d * F + lane],      nrm * H[s * F + lane]);
        atomicAdd(&out[d * F + 64 + lane], nrm * H[s * F + 64 + lane]);
    }
}

// ---- in-place ReLU ----
__global__ void k_relu(float* __restrict__ x, int n) {
    int i = blockIdx.x * blockDim.x + threadIdx.x;
    if (i < n) x[i] = fmaxf(x[i], 0.f);
}

extern "C" void kernel_launch(void* const* d_in, const int* in_sizes, int n_in,
                              void* d_out, int out_size, void* d_ws, size_t ws_size,
                              hipStream_t stream) {
    const float* x  = (const float*)d_in[0];
    const int*   ei = (const int*)  d_in[1];
    const float* W1 = (const float*)d_in[2];
    const float* b1 = (const float*)d_in[3];
    const float* W2 = (const float*)d_in[4];
    const float* b2 = (const float*)d_in[5];
    float* out = (float*)d_out;

    const int E = in_sizes[1] / 2;        // 800000
    const int* srcp = ei;                 // edge_index[0]
    const int* dstp = ei + E;             // edge_index[1]

    float* dinv = (float*)d_ws;                 // N floats
    float* H    = dinv + N_NODES;               // N*F floats (GEMM output)

    const int NF = N_NODES * F;

    // degrees -> dinv (shared by both layers)
    hipMemsetAsync(dinv, 0, N_NODES * sizeof(float), stream);
    k_count<<<(E + 255) / 256, 256, 0, stream>>>(dstp, E, dinv);
    k_rsqrt<<<(N_NODES + 255) / 256, 256, 0, stream>>>(dinv, N_NODES);

    // ---- layer 1 ----
    k_gemm   <<<1024, 256, 0, stream>>>(x, W1, H, N_NODES);
    k_init   <<<(NF + 255) / 256, 256, 0, stream>>>(H, b1, dinv, out, N_NODES);
    k_scatter<<<2048, 256, 0, stream>>>(srcp, dstp, E, dinv, H, out);
    k_relu   <<<(NF + 255) / 256, 256, 0, stream>>>(out, NF);

    // ---- layer 2 (reads a1 from d_out, H reused, then overwrites d_out) ----
    k_gemm   <<<1024, 256, 0, stream>>>(out, W2, H, N_NODES);
    k_init   <<<(NF + 255) / 256, 256, 0, stream>>>(H, b2, dinv, out, N_NODES);
    k_scatter<<<2048, 256, 0, stream>>>(srcp, dstp, E, dinv, H, out);
    k_relu   <<<(NF + 255) / 256, 256, 0, stream>>>(out, NF);
}

// Round 2
// 850.299 us; speedup vs baseline: 1.4356x; 1.4356x over previous
//
#include <hip/hip_runtime.h>

#define N_NODES 50000
#define F 128

// ---- degree histogram over real edges ----
__global__ void k_count(const int* __restrict__ dst, int E, int* __restrict__ deg) {
    int i = blockIdx.x * blockDim.x + threadIdx.x;
    if (i < E) atomicAdd(&deg[dst[i]], 1);
}

// ---- single-block exclusive scan: offsets/cursor + dinv = rsqrt(deg+1) ----
__global__ __launch_bounds__(1024) void k_scan(const int* __restrict__ deg,
                                               int* __restrict__ offsets,
                                               int* __restrict__ cursor,
                                               float* __restrict__ dinv, int E) {
    __shared__ int part[1024];
    const int t = threadIdx.x;
    const int CH = (N_NODES + 1023) / 1024;          // 49
    const int lo = t * CH, hi = min(lo + CH, N_NODES);
    int s = 0;
    for (int i = lo; i < hi; ++i) s += deg[i];
    part[t] = s;
    __syncthreads();
    for (int d = 1; d < 1024; d <<= 1) {             // Hillis-Steele inclusive scan
        int v = (t >= d) ? part[t - d] : 0;
        __syncthreads();
        part[t] += v;
        __syncthreads();
    }
    int run = (t > 0) ? part[t - 1] : 0;             // exclusive prefix of this chunk
    for (int i = lo; i < hi; ++i) {
        offsets[i] = run;
        cursor[i]  = run;
        const int dg = deg[i];
        dinv[i] = rsqrtf((float)(dg + 1));           // +1 self loop
        run += dg;
    }
    if (t == 1023) offsets[N_NODES] = E;
}

// ---- counting-sort fill: csr_src[pos] = src ----
__global__ void k_fill(const int* __restrict__ src, const int* __restrict__ dst, int E,
                       int* __restrict__ cursor, int* __restrict__ csr_src) {
    int i = blockIdx.x * blockDim.x + threadIdx.x;
    if (i < E) {
        const int d   = dst[i];
        const int pos = atomicAdd(&cursor[d], 1);
        csr_src[pos] = src[i];
    }
}

// ---- Hs = dinv[row] * (X @ W)   (W staged in LDS, one wave per row) ----
__global__ __launch_bounds__(256) void k_gemm(const float* __restrict__ X,
                                              const float* __restrict__ W,
                                              const float* __restrict__ dinv,
                                              float* __restrict__ Hs, int nrows) {
    __shared__ float Ws[F * F];
    for (int i = threadIdx.x; i < F * F; i += 256) Ws[i] = W[i];
    __syncthreads();
    const int wid  = threadIdx.x >> 6;
    const int lane = threadIdx.x & 63;
    const int gw   = blockIdx.x * 4 + wid;
    const int nw   = gridDim.x * 4;
    for (int row = gw; row < nrows; row += nw) {
        const float x0 = X[row * F + lane];
        const float x1 = X[row * F + 64 + lane];
        float acc0 = 0.f, acc1 = 0.f;
#pragma unroll
        for (int k = 0; k < 64; ++k) {
            const float xv = __shfl(x0, k);
            acc0 += xv * Ws[k * F + lane];
            acc1 += xv * Ws[k * F + 64 + lane];
        }
#pragma unroll
        for (int k = 0; k < 64; ++k) {
            const float xv = __shfl(x1, k);
            acc0 += xv * Ws[(64 + k) * F + lane];
            acc1 += xv * Ws[(64 + k) * F + 64 + lane];
        }
        const float dn = dinv[row];
        Hs[row * F + lane]      = dn * acc0;
        Hs[row * F + 64 + lane] = dn * acc1;
    }
}

// ---- node-centric gather: out[n] = relu(b + dinv[n]*(Hs[n] + sum Hs[src])) ----
__global__ __launch_bounds__(256) void k_gather(const int* __restrict__ offsets,
                                                const int* __restrict__ csr_src,
                                                const float* __restrict__ Hs,
                                                const float* __restrict__ dinv,
                                                const float* __restrict__ b,
                                                float* __restrict__ out) {
    const int wid  = (blockIdx.x * blockDim.x + threadIdx.x) >> 6;
    const int lane = threadIdx.x & 63;
    const int nw   = (gridDim.x * blockDim.x) >> 6;
    for (int n = wid; n < N_NODES; n += nw) {
        const int beg = offsets[n], end = offsets[n + 1];
        float a0 = Hs[n * F + lane];              // self-loop message (pre-scaled)
        float a1 = Hs[n * F + 64 + lane];
        int e = beg;
        for (; e + 1 < end; e += 2) {             // 2-edge unroll for MLP
            const int s0 = csr_src[e];
            const int s1 = csr_src[e + 1];
            a0 += Hs[s0 * F + lane];
            a1 += Hs[s0 * F + 64 + lane];
            a0 += Hs[s1 * F + lane];
            a1 += Hs[s1 * F + 64 + lane];
        }
        if (e < end) {
            const int s0 = csr_src[e];
            a0 += Hs[s0 * F + lane];
            a1 += Hs[s0 * F + 64 + lane];
        }
        const float dn = dinv[n];
        out[n * F + lane]      = fmaxf(fmaf(dn, a0, b[lane]),      0.f);
        out[n * F + 64 + lane] = fmaxf(fmaf(dn, a1, b[64 + lane]), 0.f);
    }
}

extern "C" void kernel_launch(void* const* d_in, const int* in_sizes, int n_in,
                              void* d_out, int out_size, void* d_ws, size_t ws_size,
                              hipStream_t stream) {
    const float* x  = (const float*)d_in[0];
    const int*   ei = (const int*)  d_in[1];
    const float* W1 = (const float*)d_in[2];
    const float* b1 = (const float*)d_in[3];
    const float* W2 = (const float*)d_in[4];
    const float* b2 = (const float*)d_in[5];
    float* out = (float*)d_out;

    const int E = in_sizes[1] / 2;        // 800000
    const int* srcp = ei;                 // edge_index[0]
    const int* dstp = ei + E;             // edge_index[1]

    // ---- workspace carve-up ----
    int*   deg     = (int*)d_ws;                  // N
    int*   offsets = deg + N_NODES;               // N+1
    int*   cursor  = offsets + N_NODES + 1;       // N
    int*   csr_src = cursor + N_NODES;            // E
    float* dinv    = (float*)(csr_src + E);       // N
    float* Hs      = dinv + N_NODES;              // N*F

    // ---- CSR build (shared by both layers) ----
    hipMemsetAsync(deg, 0, N_NODES * sizeof(int), stream);
    k_count<<<(E + 255) / 256, 256, 0, stream>>>(dstp, E, deg);
    k_scan <<<1, 1024, 0, stream>>>(deg, offsets, cursor, dinv, E);
    k_fill <<<(E + 255) / 256, 256, 0, stream>>>(srcp, dstp, E, cursor, csr_src);

    // ---- layer 1 ----
    k_gemm  <<<1024, 256, 0, stream>>>(x, W1, dinv, Hs, N_NODES);
    k_gather<<<2048, 256, 0, stream>>>(offsets, csr_src, Hs, dinv, b1, out);

    // ---- layer 2 ----
    k_gemm  <<<1024, 256, 0, stream>>>(out, W2, dinv, Hs, N_NODES);
    k_gather<<<2048, 256, 0, stream>>>(offsets, csr_src, Hs, dinv, b2, out);
}

// Round 3
// 445.620 us; speedup vs baseline: 2.7392x; 1.9081x over previous
//
#include <hip/hip_runtime.h>

#define N_NODES 50000
#define F 128

// ---- degree histogram over real edges ----
__global__ void k_count(const int* __restrict__ dst, int E, int* __restrict__ deg) {
    int i = blockIdx.x * blockDim.x + threadIdx.x;
    if (i < E) atomicAdd(&deg[dst[i]], 1);
}

// ---- single-block exclusive scan: offsets/cursor + dinv = rsqrt(deg+1) ----
__global__ __launch_bounds__(1024) void k_scan(const int* __restrict__ deg,
                                               int* __restrict__ offsets,
                                               int* __restrict__ cursor,
                                               float* __restrict__ dinv, int E) {
    __shared__ int part[1024];
    const int t = threadIdx.x;
    const int CH = (N_NODES + 1023) / 1024;          // 49
    const int lo = t * CH, hi = min(lo + CH, N_NODES);
    int s = 0;
    for (int i = lo; i < hi; ++i) s += deg[i];
    part[t] = s;
    __syncthreads();
    for (int d = 1; d < 1024; d <<= 1) {             // Hillis-Steele inclusive scan
        int v = (t >= d) ? part[t - d] : 0;
        __syncthreads();
        part[t] += v;
        __syncthreads();
    }
    int run = (t > 0) ? part[t - 1] : 0;             // exclusive prefix of this chunk
    for (int i = lo; i < hi; ++i) {
        offsets[i] = run;
        cursor[i]  = run;
        const int dg = deg[i];
        dinv[i] = rsqrtf((float)(dg + 1));           // +1 self loop
        run += dg;
    }
    if (t == 1023) offsets[N_NODES] = E;
}

// ---- counting-sort fill: csr_src[pos] = src ----
__global__ void k_fill(const int* __restrict__ src, const int* __restrict__ dst, int E,
                       int* __restrict__ cursor, int* __restrict__ csr_src) {
    int i = blockIdx.x * blockDim.x + threadIdx.x;
    if (i < E) {
        const int d   = dst[i];
        const int pos = atomicAdd(&cursor[d], 1);
        csr_src[pos] = src[i];
    }
}

// ---- Hs = dinv[row] * (X @ W) ----
// lane = column pair (2*lane, 2*lane+1): X[row][k] is wave-uniform -> scalar
// loads through K$; W staged in LDS as float2[k][64], one ds_read_b64 per k
// feeding 16 FMAs (8 rows x 2 cols). 512 threads, 64 KB LDS -> 2 blocks/CU.
__global__ __launch_bounds__(512) void k_gemm(const float* __restrict__ X,
                                              const float* __restrict__ W,
                                              const float* __restrict__ dinv,
                                              float* __restrict__ Hs, int nrows) {
    __shared__ float2 Ws[F * 64];                    // Ws[k*64 + j] = W[k][2j..2j+1]
    const float2* Wv = (const float2*)W;
    for (int i = threadIdx.x; i < F * 64; i += 512) Ws[i] = Wv[i];
    __syncthreads();

    const int wid   = threadIdx.x >> 6;              // 0..7
    const int lane  = threadIdx.x & 63;
    const int ntile = nrows >> 3;                    // 8 rows per wave-tile (50000/8)
    float2* __restrict__ Hv = (float2*)Hs;

    int tile = __builtin_amdgcn_readfirstlane(blockIdx.x * 8 + wid);
    const int stride = gridDim.x * 8;
    for (; tile < ntile; tile += stride) {
        const int r0 = tile * 8;
        const float* __restrict__ Xr = X + r0 * F;   // wave-uniform base
        float2 acc[8];
#pragma unroll
        for (int r = 0; r < 8; ++r) acc[r] = make_float2(0.f, 0.f);
#pragma unroll 8
        for (int k = 0; k < F; ++k) {
            const float2 w = Ws[k * 64 + lane];
#pragma unroll
            for (int r = 0; r < 8; ++r) {
                const float xv = Xr[r * F + k];      // uniform -> s_load
                acc[r].x = fmaf(xv, w.x, acc[r].x);
                acc[r].y = fmaf(xv, w.y, acc[r].y);
            }
        }
#pragma unroll
        for (int r = 0; r < 8; ++r) {
            const float dn = dinv[r0 + r];
            float2 o;
            o.x = dn * acc[r].x;
            o.y = dn * acc[r].y;
            Hv[(r0 + r) * 64 + lane] = o;
        }
    }
}

// ---- node-centric gather: out[n] = relu(b + dinv[n]*(Hs[n] + sum Hs[src])) ----
__global__ __launch_bounds__(256) void k_gather(const int* __restrict__ offsets,
                                                const int* __restrict__ csr_src,
                                                const float* __restrict__ Hs,
                                                const float* __restrict__ dinv,
                                                const float* __restrict__ b,
                                                float* __restrict__ out) {
    const int wid  = (blockIdx.x * blockDim.x + threadIdx.x) >> 6;
    const int lane = threadIdx.x & 63;
    const int nw   = (gridDim.x * blockDim.x) >> 6;
    const float2* __restrict__ Hv = (const float2*)Hs;
    float2* __restrict__ outv = (float2*)out;
    const float2 bb = ((const float2*)b)[lane];
    for (int n = wid; n < N_NODES; n += nw) {
        const int beg = offsets[n], end = offsets[n + 1];
        float2 a0 = Hv[n * 64 + lane];               // self-loop message (pre-scaled)
        float2 a1 = make_float2(0.f, 0.f);
        int e = beg;
        for (; e + 1 < end; e += 2) {                // 2-edge unroll for MLP
            const int s0 = csr_src[e];
            const int s1 = csr_src[e + 1];
            const float2 h0 = Hv[s0 * 64 + lane];
            const float2 h1 = Hv[s1 * 64 + lane];
            a0.x += h0.x; a0.y += h0.y;
            a1.x += h1.x; a1.y += h1.y;
        }
        if (e < end) {
            const int s0 = csr_src[e];
            const float2 h0 = Hv[s0 * 64 + lane];
            a0.x += h0.x; a0.y += h0.y;
        }
        const float dn = dinv[n];
        float2 o;
        o.x = fmaxf(fmaf(dn, a0.x + a1.x, bb.x), 0.f);
        o.y = fmaxf(fmaf(dn, a0.y + a1.y, bb.y), 0.f);
        outv[n * 64 + lane] = o;
    }
}

extern "C" void kernel_launch(void* const* d_in, const int* in_sizes, int n_in,
                              void* d_out, int out_size, void* d_ws, size_t ws_size,
                              hipStream_t stream) {
    const float* x  = (const float*)d_in[0];
    const int*   ei = (const int*)  d_in[1];
    const float* W1 = (const float*)d_in[2];
    const float* b1 = (const float*)d_in[3];
    const float* W2 = (const float*)d_in[4];
    const float* b2 = (const float*)d_in[5];
    float* out = (float*)d_out;

    const int E = in_sizes[1] / 2;        // 800000
    const int* srcp = ei;                 // edge_index[0]
    const int* dstp = ei + E;             // edge_index[1]

    // ---- workspace carve-up (padded so Hs is 16B-aligned) ----
    int*   deg     = (int*)d_ws;                  // N
    int*   offsets = deg + N_NODES;               // N+2 (pad for alignment)
    int*   cursor  = offsets + N_NODES + 2;       // N
    int*   csr_src = cursor + N_NODES;            // E
    float* dinv    = (float*)(csr_src + E);       // N
    float* Hs      = dinv + N_NODES;              // N*F, 16B-aligned

    // ---- CSR build (shared by both layers) ----
    hipMemsetAsync(deg, 0, N_NODES * sizeof(int), stream);
    k_count<<<(E + 255) / 256, 256, 0, stream>>>(dstp, E, deg);
    k_scan <<<1, 1024, 0, stream>>>(deg, offsets, cursor, dinv, E);
    k_fill <<<(E + 255) / 256, 256, 0, stream>>>(srcp, dstp, E, cursor, csr_src);

    const int gemm_blocks = (N_NODES / 8 + 7) / 8;   // 782

    // ---- layer 1 ----
    k_gemm  <<<gemm_blocks, 512, 0, stream>>>(x, W1, dinv, Hs, N_NODES);
    k_gather<<<2048, 256, 0, stream>>>(offsets, csr_src, Hs, dinv, b1, out);

    // ---- layer 2 ----
    k_gemm  <<<gemm_blocks, 512, 0, stream>>>(out, W2, dinv, Hs, N_NODES);
    k_gather<<<2048, 256, 0, stream>>>(offsets, csr_src, Hs, dinv, b2, out);
}

// Round 4
// 322.803 us; speedup vs baseline: 3.7814x; 1.3805x over previous
//
#include <hip/hip_runtime.h>

#define N_NODES 50000
#define F 128
#define SCAN_B 1024
#define SCAN_NB ((N_NODES + SCAN_B - 1) / SCAN_B)   // 49

// ---- degree histogram over real edges ----
__global__ void k_count(const int* __restrict__ dst, int E, int* __restrict__ deg) {
    int i = blockIdx.x * blockDim.x + threadIdx.x;
    if (i < E) atomicAdd(&deg[dst[i]], 1);
}

// ---- per-block sum of 1024 degrees -> partials[block] ----
__global__ __launch_bounds__(1024) void k_bsum(const int* __restrict__ deg,
                                               int* __restrict__ partials) {
    const int i = blockIdx.x * SCAN_B + threadIdx.x;
    int v = (i < N_NODES) ? deg[i] : 0;
#pragma unroll
    for (int d = 1; d < 64; d <<= 1) v += __shfl_xor(v, d);
    __shared__ int ws[16];
    if ((threadIdx.x & 63) == 0) ws[threadIdx.x >> 6] = v;
    __syncthreads();
    if (threadIdx.x < 16) {
        int s = ws[threadIdx.x];
#pragma unroll
        for (int d = 1; d < 16; d <<= 1) s += __shfl_xor(s, d);
        if (threadIdx.x == 0) partials[blockIdx.x] = s;
    }
}

// ---- 1-wave exclusive scan of the 49 partials ----
__global__ void k_pscan(int* __restrict__ partials) {
    const int t = threadIdx.x;
    const int x = (t < SCAN_NB) ? partials[t] : 0;
    int inc = x;
#pragma unroll
    for (int d = 1; d < 64; d <<= 1) {
        const int u = __shfl_up(inc, d);
        if (t >= d) inc += u;
    }
    if (t < SCAN_NB) partials[t] = inc - x;          // exclusive
}

// ---- block-local scan + global offset: offsets/cursor/dinv ----
__global__ __launch_bounds__(1024) void k_offsets(const int* __restrict__ deg,
                                                  const int* __restrict__ partials,
                                                  int* __restrict__ offsets,
                                                  int* __restrict__ cursor,
                                                  float* __restrict__ dinv, int E) {
    const int i = blockIdx.x * SCAN_B + threadIdx.x;
    const int d = (i < N_NODES) ? deg[i] : 0;
    const int lane = threadIdx.x & 63, wid = threadIdx.x >> 6;
    int inc = d;
#pragma unroll
    for (int dd = 1; dd < 64; dd <<= 1) {
        const int u = __shfl_up(inc, dd);
        if (lane >= dd) inc += u;
    }
    __shared__ int wsum[16], wpre[16];
    if (lane == 63) wsum[wid] = inc;
    __syncthreads();
    if (threadIdx.x < 16) {
        const int s = wsum[threadIdx.x];
        int is = s;
#pragma unroll
        for (int dd = 1; dd < 16; dd <<= 1) {
            const int u = __shfl_up(is, dd);
            if (threadIdx.x >= dd) is += u;
        }
        wpre[threadIdx.x] = is - s;
    }
    __syncthreads();
    const int ex = (inc - d) + wpre[wid] + partials[blockIdx.x];
    if (i <= N_NODES) offsets[i] = ex;               // offsets[N_NODES] == E
    if (i < N_NODES) {
        cursor[i] = ex;
        dinv[i]   = rsqrtf((float)(d + 1));          // +1 self loop
    }
}

// ---- counting-sort fill: csr_src[pos] = src ----
__global__ void k_fill(const int* __restrict__ src, const int* __restrict__ dst, int E,
                       int* __restrict__ cursor, int* __restrict__ csr_src) {
    int i = blockIdx.x * blockDim.x + threadIdx.x;
    if (i < E) {
        const int d   = dst[i];
        const int pos = atomicAdd(&cursor[d], 1);
        csr_src[pos] = src[i];
    }
}

// ---- Hs = dinv[row] * (X @ W) ----
// lane = column pair: X[row][k] wave-uniform -> scalar loads; W in LDS.
__global__ __launch_bounds__(512) void k_gemm(const float* __restrict__ X,
                                              const float* __restrict__ W,
                                              const float* __restrict__ dinv,
                                              float* __restrict__ Hs, int nrows) {
    __shared__ float2 Ws[F * 64];                    // Ws[k*64 + j] = W[k][2j..2j+1]
    const float2* Wv = (const float2*)W;
    for (int i = threadIdx.x; i < F * 64; i += 512) Ws[i] = Wv[i];
    __syncthreads();

    const int wid   = threadIdx.x >> 6;
    const int lane  = threadIdx.x & 63;
    const int ntile = nrows >> 3;                    // 8 rows per wave-tile
    float2* __restrict__ Hv = (float2*)Hs;

    int tile = __builtin_amdgcn_readfirstlane(blockIdx.x * 8 + wid);
    const int stride = gridDim.x * 8;
    for (; tile < ntile; tile += stride) {
        const int r0 = tile * 8;
        const float* __restrict__ Xr = X + r0 * F;
        float2 acc[8];
#pragma unroll
        for (int r = 0; r < 8; ++r) acc[r] = make_float2(0.f, 0.f);
#pragma unroll 8
        for (int k = 0; k < F; ++k) {
            const float2 w = Ws[k * 64 + lane];
#pragma unroll
            for (int r = 0; r < 8; ++r) {
                const float xv = Xr[r * F + k];
                acc[r].x = fmaf(xv, w.x, acc[r].x);
                acc[r].y = fmaf(xv, w.y, acc[r].y);
            }
        }
#pragma unroll
        for (int r = 0; r < 8; ++r) {
            const float dn = dinv[r0 + r];
            float2 o;
            o.x = dn * acc[r].x;
            o.y = dn * acc[r].y;
            Hv[(r0 + r) * 64 + lane] = o;
        }
    }
}

// ---- node gather, float4: halves of the wave take alternating edges ----
__global__ __launch_bounds__(256) void k_gather(const int* __restrict__ offsets,
                                                const int* __restrict__ csr_src,
                                                const float* __restrict__ Hs,
                                                const float* __restrict__ dinv,
                                                const float* __restrict__ b,
                                                float* __restrict__ out) {
    const int wid  = (blockIdx.x * blockDim.x + threadIdx.x) >> 6;
    const int lane = threadIdx.x & 63;
    const int half = lane >> 5;                      // 0/1
    const int l32  = lane & 31;
    const int nw   = (gridDim.x * blockDim.x) >> 6;
    const float4* __restrict__ Hv = (const float4*)Hs;   // row = 32 float4
    float4* __restrict__ outv = (float4*)out;
    const float4 bb = ((const float4*)b)[l32];
    for (int n = wid; n < N_NODES; n += nw) {
        const int beg = offsets[n], end = offsets[n + 1];
        float4 a = make_float4(0.f, 0.f, 0.f, 0.f);
        for (int e = beg + half; e < end; e += 2) {
            const int s = csr_src[e];
            const float4 h = Hv[s * 32 + l32];
            a.x += h.x; a.y += h.y; a.z += h.z; a.w += h.w;
        }
        a.x += __shfl_xor(a.x, 32);
        a.y += __shfl_xor(a.y, 32);
        a.z += __shfl_xor(a.z, 32);
        a.w += __shfl_xor(a.w, 32);
        if (half == 0) {
            const float4 self = Hv[n * 32 + l32];    // pre-scaled self message
            const float dn = dinv[n];
            float4 o;
            o.x = fmaxf(fmaf(dn, a.x + self.x, bb.x), 0.f);
            o.y = fmaxf(fmaf(dn, a.y + self.y, bb.y), 0.f);
            o.z = fmaxf(fmaf(dn, a.z + self.z, bb.z), 0.f);
            o.w = fmaxf(fmaf(dn, a.w + self.w, bb.w), 0.f);
            outv[n * 32 + l32] = o;
        }
    }
}

extern "C" void kernel_launch(void* const* d_in, const int* in_sizes, int n_in,
                              void* d_out, int out_size, void* d_ws, size_t ws_size,
                              hipStream_t stream) {
    const float* x  = (const float*)d_in[0];
    const int*   ei = (const int*)  d_in[1];
    const float* W1 = (const float*)d_in[2];
    const float* b1 = (const float*)d_in[3];
    const float* W2 = (const float*)d_in[4];
    const float* b2 = (const float*)d_in[5];
    float* out = (float*)d_out;

    const int E = in_sizes[1] / 2;        // 800000
    const int* srcp = ei;                 // edge_index[0]
    const int* dstp = ei + E;             // edge_index[1]

    // ---- workspace carve-up (Hs 16B-aligned: prefix = 1000004 ints) ----
    int*   deg      = (int*)d_ws;                 // 50000
    int*   offsets  = deg + N_NODES;              // 50004 (N+1 used, padded)
    int*   cursor   = offsets + N_NODES + 4;      // 50000
    int*   csr_src  = cursor + N_NODES;           // 800000
    float* dinv     = (float*)(csr_src + E);      // 50000
    float* Hs       = dinv + N_NODES;             // N*F, 16B-aligned
    int*   partials = (int*)(Hs + N_NODES * F);   // SCAN_NB

    // ---- CSR build (shared by both layers) ----
    hipMemsetAsync(deg, 0, N_NODES * sizeof(int), stream);
    k_count  <<<(E + 255) / 256, 256, 0, stream>>>(dstp, E, deg);
    k_bsum   <<<SCAN_NB, SCAN_B, 0, stream>>>(deg, partials);
    k_pscan  <<<1, 64, 0, stream>>>(partials);
    k_offsets<<<SCAN_NB, SCAN_B, 0, stream>>>(deg, partials, offsets, cursor, dinv, E);
    k_fill   <<<(E + 255) / 256, 256, 0, stream>>>(srcp, dstp, E, cursor, csr_src);

    const int gemm_blocks = (N_NODES / 8 + 7) / 8;   // 782

    // ---- layer 1 ----
    k_gemm  <<<gemm_blocks, 512, 0, stream>>>(x, W1, dinv, Hs, N_NODES);
    k_gather<<<2048, 256, 0, stream>>>(offsets, csr_src, Hs, dinv, b1, out);

    // ---- layer 2 ----
    k_gemm  <<<gemm_blocks, 512, 0, stream>>>(out, W2, dinv, Hs, N_NODES);
    k_gather<<<2048, 256, 0, stream>>>(offsets, csr_src, Hs, dinv, b2, out);
}

// Round 5
// 315.285 us; speedup vs baseline: 3.8716x; 1.0238x over previous
//
#include <hip/hip_runtime.h>

#define N_NODES 50000
#define F 128
#define SCAN_B 1024
#define SCAN_NB ((N_NODES + SCAN_B - 1) / SCAN_B)   // 49

// ---- degree histogram over real edges ----
__global__ void k_count(const int* __restrict__ dst, int E, int* __restrict__ deg) {
    int i = blockIdx.x * blockDim.x + threadIdx.x;
    if (i < E) atomicAdd(&deg[dst[i]], 1);
}

// ---- per-block sum of 1024 degrees -> partials[block] ----
__global__ __launch_bounds__(1024) void k_bsum(const int* __restrict__ deg,
                                               int* __restrict__ partials) {
    const int i = blockIdx.x * SCAN_B + threadIdx.x;
    int v = (i < N_NODES) ? deg[i] : 0;
#pragma unroll
    for (int d = 1; d < 64; d <<= 1) v += __shfl_xor(v, d);
    __shared__ int ws[16];
    if ((threadIdx.x & 63) == 0) ws[threadIdx.x >> 6] = v;
    __syncthreads();
    if (threadIdx.x < 16) {
        int s = ws[threadIdx.x];
#pragma unroll
        for (int d = 1; d < 16; d <<= 1) s += __shfl_xor(s, d);
        if (threadIdx.x == 0) partials[blockIdx.x] = s;
    }
}

// ---- 1-wave exclusive scan of the 49 partials ----
__global__ void k_pscan(int* __restrict__ partials) {
    const int t = threadIdx.x;
    const int x = (t < SCAN_NB) ? partials[t] : 0;
    int inc = x;
#pragma unroll
    for (int d = 1; d < 64; d <<= 1) {
        const int u = __shfl_up(inc, d);
        if (t >= d) inc += u;
    }
    if (t < SCAN_NB) partials[t] = inc - x;          // exclusive
}

// ---- block-local scan + global offset: offsets/cursor/dinv ----
__global__ __launch_bounds__(1024) void k_offsets(const int* __restrict__ deg,
                                                  const int* __restrict__ partials,
                                                  int* __restrict__ offsets,
                                                  int* __restrict__ cursor,
                                                  float* __restrict__ dinv, int E) {
    const int i = blockIdx.x * SCAN_B + threadIdx.x;
    const int d = (i < N_NODES) ? deg[i] : 0;
    const int lane = threadIdx.x & 63, wid = threadIdx.x >> 6;
    int inc = d;
#pragma unroll
    for (int dd = 1; dd < 64; dd <<= 1) {
        const int u = __shfl_up(inc, dd);
        if (lane >= dd) inc += u;
    }
    __shared__ int wsum[16], wpre[16];
    if (lane == 63) wsum[wid] = inc;
    __syncthreads();
    if (threadIdx.x < 16) {
        const int s = wsum[threadIdx.x];
        int is = s;
#pragma unroll
        for (int dd = 1; dd < 16; dd <<= 1) {
            const int u = __shfl_up(is, dd);
            if (threadIdx.x >= dd) is += u;
        }
        wpre[threadIdx.x] = is - s;
    }
    __syncthreads();
    const int ex = (inc - d) + wpre[wid] + partials[blockIdx.x];
    if (i <= N_NODES) offsets[i] = ex;               // offsets[N_NODES] == E
    if (i < N_NODES) {
        cursor[i] = ex;
        dinv[i]   = rsqrtf((float)(d + 1));          // +1 self loop
    }
}

// ---- counting-sort fill: csr_src[pos] = src ----
__global__ void k_fill(const int* __restrict__ src, const int* __restrict__ dst, int E,
                       int* __restrict__ cursor, int* __restrict__ csr_src) {
    int i = blockIdx.x * blockDim.x + threadIdx.x;
    if (i < E) {
        const int d   = dst[i];
        const int pos = atomicAdd(&cursor[d], 1);
        csr_src[pos] = src[i];
    }
}

// ---- Hs = dinv[row] * (X @ W) ----
// lane = column pair: X[row][k] wave-uniform -> scalar loads; W in LDS.
__global__ __launch_bounds__(512) void k_gemm(const float* __restrict__ X,
                                              const float* __restrict__ W,
                                              const float* __restrict__ dinv,
                                              float* __restrict__ Hs, int nrows) {
    __shared__ float2 Ws[F * 64];                    // Ws[k*64 + j] = W[k][2j..2j+1]
    const float2* Wv = (const float2*)W;
    for (int i = threadIdx.x; i < F * 64; i += 512) Ws[i] = Wv[i];
    __syncthreads();

    const int wid   = threadIdx.x >> 6;
    const int lane  = threadIdx.x & 63;
    const int ntile = nrows >> 3;                    // 8 rows per wave-tile
    float2* __restrict__ Hv = (float2*)Hs;

    int tile = __builtin_amdgcn_readfirstlane(blockIdx.x * 8 + wid);
    const int stride = gridDim.x * 8;
    for (; tile < ntile; tile += stride) {
        const int r0 = tile * 8;
        const float* __restrict__ Xr = X + r0 * F;
        float2 acc[8];
#pragma unroll
        for (int r = 0; r < 8; ++r) acc[r] = make_float2(0.f, 0.f);
#pragma unroll 8
        for (int k = 0; k < F; ++k) {
            const float2 w = Ws[k * 64 + lane];
#pragma unroll
            for (int r = 0; r < 8; ++r) {
                const float xv = Xr[r * F + k];
                acc[r].x = fmaf(xv, w.x, acc[r].x);
                acc[r].y = fmaf(xv, w.y, acc[r].y);
            }
        }
#pragma unroll
        for (int r = 0; r < 8; ++r) {
            const float dn = dinv[r0 + r];
            float2 o;
            o.x = dn * acc[r].x;
            o.y = dn * acc[r].y;
            Hv[(r0 + r) * 64 + lane] = o;
        }
    }
}

// ---- node gather: one 32-lane group per node, 4-deep edge unroll ----
// 8 gathers in flight per wave (vs 2 before) to cover L3/HBM latency.
__global__ __launch_bounds__(256) void k_gather(const int* __restrict__ offsets,
                                                const int* __restrict__ csr_src,
                                                const float* __restrict__ Hs,
                                                const float* __restrict__ dinv,
                                                const float* __restrict__ b,
                                                float* __restrict__ out) {
    const int tid = blockIdx.x * blockDim.x + threadIdx.x;
    const int g   = tid >> 5;                        // global 32-lane group
    const int l32 = threadIdx.x & 31;
    const int ng  = (gridDim.x * blockDim.x) >> 5;
    const float4* __restrict__ Hv = (const float4*)Hs;   // row = 32 float4
    float4* __restrict__ outv = (float4*)out;
    const float4 bb = ((const float4*)b)[l32];
    for (int n = g; n < N_NODES; n += ng) {
        const int beg = offsets[n], end = offsets[n + 1];
        float4 a0 = Hv[n * 32 + l32];                // pre-scaled self message
        float4 a1 = make_float4(0.f, 0.f, 0.f, 0.f);
        float4 a2 = make_float4(0.f, 0.f, 0.f, 0.f);
        float4 a3 = make_float4(0.f, 0.f, 0.f, 0.f);
        int e = beg;
        for (; e + 3 < end; e += 4) {
            const int s0 = csr_src[e];
            const int s1 = csr_src[e + 1];
            const int s2 = csr_src[e + 2];
            const int s3 = csr_src[e + 3];
            const float4 h0 = Hv[s0 * 32 + l32];
            const float4 h1 = Hv[s1 * 32 + l32];
            const float4 h2 = Hv[s2 * 32 + l32];
            const float4 h3 = Hv[s3 * 32 + l32];
            a0.x += h0.x; a0.y += h0.y; a0.z += h0.z; a0.w += h0.w;
            a1.x += h1.x; a1.y += h1.y; a1.z += h1.z; a1.w += h1.w;
            a2.x += h2.x; a2.y += h2.y; a2.z += h2.z; a2.w += h2.w;
            a3.x += h3.x; a3.y += h3.y; a3.z += h3.z; a3.w += h3.w;
        }
        for (; e < end; ++e) {
            const int s0 = csr_src[e];
            const float4 h0 = Hv[s0 * 32 + l32];
            a1.x += h0.x; a1.y += h0.y; a1.z += h0.z; a1.w += h0.w;
        }
        const float dn = dinv[n];
        float4 o;
        o.x = fmaxf(fmaf(dn, (a0.x + a1.x) + (a2.x + a3.x), bb.x), 0.f);
        o.y = fmaxf(fmaf(dn, (a0.y + a1.y) + (a2.y + a3.y), bb.y), 0.f);
        o.z = fmaxf(fmaf(dn, (a0.z + a1.z) + (a2.z + a3.z), bb.z), 0.f);
        o.w = fmaxf(fmaf(dn, (a0.w + a1.w) + (a2.w + a3.w), bb.w), 0.f);
        outv[n * 32 + l32] = o;
    }
}

extern "C" void kernel_launch(void* const* d_in, const int* in_sizes, int n_in,
                              void* d_out, int out_size, void* d_ws, size_t ws_size,
                              hipStream_t stream) {
    const float* x  = (const float*)d_in[0];
    const int*   ei = (const int*)  d_in[1];
    const float* W1 = (const float*)d_in[2];
    const float* b1 = (const float*)d_in[3];
    const float* W2 = (const float*)d_in[4];
    const float* b2 = (const float*)d_in[5];
    float* out = (float*)d_out;

    const int E = in_sizes[1] / 2;        // 800000
    const int* srcp = ei;                 // edge_index[0]
    const int* dstp = ei + E;             // edge_index[1]

    // ---- workspace carve-up (Hs 16B-aligned: prefix = 1000004 ints) ----
    int*   deg      = (int*)d_ws;                 // 50000
    int*   offsets  = deg + N_NODES;              // 50004 (N+1 used, padded)
    int*   cursor   = offsets + N_NODES + 4;      // 50000
    int*   csr_src  = cursor + N_NODES;           // 800000
    float* dinv     = (float*)(csr_src + E);      // 50000
    float* Hs       = dinv + N_NODES;             // N*F, 16B-aligned
    int*   partials = (int*)(Hs + N_NODES * F);   // SCAN_NB

    // ---- CSR build (shared by both layers) ----
    hipMemsetAsync(deg, 0, N_NODES * sizeof(int), stream);
    k_count  <<<(E + 255) / 256, 256, 0, stream>>>(dstp, E, deg);
    k_bsum   <<<SCAN_NB, SCAN_B, 0, stream>>>(deg, partials);
    k_pscan  <<<1, 64, 0, stream>>>(partials);
    k_offsets<<<SCAN_NB, SCAN_B, 0, stream>>>(deg, partials, offsets, cursor, dinv, E);
    k_fill   <<<(E + 255) / 256, 256, 0, stream>>>(srcp, dstp, E, cursor, csr_src);

    const int gemm_blocks = (N_NODES / 8 + 7) / 8;   // 782

    // ---- layer 1 ----
    k_gemm  <<<gemm_blocks, 512, 0, stream>>>(x, W1, dinv, Hs, N_NODES);
    k_gather<<<2048, 256, 0, stream>>>(offsets, csr_src, Hs, dinv, b1, out);

    // ---- layer 2 ----
    k_gemm  <<<gemm_blocks, 512, 0, stream>>>(out, W2, dinv, Hs, N_NODES);
    k_gather<<<2048, 256, 0, stream>>>(offsets, csr_src, Hs, dinv, b2, out);
}

// Round 6
// 255.242 us; speedup vs baseline: 4.7824x; 1.2352x over previous
//
#include <hip/hip_runtime.h>
#include <hip/hip_fp16.h>

#define N_NODES 50000
#define F 128
#define SCAN_B 1024
#define SCAN_NB ((N_NODES + SCAN_B - 1) / SCAN_B)   // 49

// ---- degree histogram over real edges ----
__global__ void k_count(const int* __restrict__ dst, int E, int* __restrict__ deg) {
    int i = blockIdx.x * blockDim.x + threadIdx.x;
    if (i < E) atomicAdd(&deg[dst[i]], 1);
}

// ---- per-block sum of 1024 degrees -> partials[block] ----
__global__ __launch_bounds__(1024) void k_bsum(const int* __restrict__ deg,
                                               int* __restrict__ partials) {
    const int i = blockIdx.x * SCAN_B + threadIdx.x;
    int v = (i < N_NODES) ? deg[i] : 0;
#pragma unroll
    for (int d = 1; d < 64; d <<= 1) v += __shfl_xor(v, d);
    __shared__ int ws[16];
    if ((threadIdx.x & 63) == 0) ws[threadIdx.x >> 6] = v;
    __syncthreads();
    if (threadIdx.x < 16) {
        int s = ws[threadIdx.x];
#pragma unroll
        for (int d = 1; d < 16; d <<= 1) s += __shfl_xor(s, d);
        if (threadIdx.x == 0) partials[blockIdx.x] = s;
    }
}

// ---- 1-wave exclusive scan of the 49 partials ----
__global__ void k_pscan(int* __restrict__ partials) {
    const int t = threadIdx.x;
    const int x = (t < SCAN_NB) ? partials[t] : 0;
    int inc = x;
#pragma unroll
    for (int d = 1; d < 64; d <<= 1) {
        const int u = __shfl_up(inc, d);
        if (t >= d) inc += u;
    }
    if (t < SCAN_NB) partials[t] = inc - x;          // exclusive
}

// ---- block-local scan + global offset: offsets/cursor/dinv ----
__global__ __launch_bounds__(1024) void k_offsets(const int* __restrict__ deg,
                                                  const int* __restrict__ partials,
                                                  int* __restrict__ offsets,
                                                  int* __restrict__ cursor,
                                                  float* __restrict__ dinv, int E) {
    const int i = blockIdx.x * SCAN_B + threadIdx.x;
    const int d = (i < N_NODES) ? deg[i] : 0;
    const int lane = threadIdx.x & 63, wid = threadIdx.x >> 6;
    int inc = d;
#pragma unroll
    for (int dd = 1; dd < 64; dd <<= 1) {
        const int u = __shfl_up(inc, dd);
        if (lane >= dd) inc += u;
    }
    __shared__ int wsum[16], wpre[16];
    if (lane == 63) wsum[wid] = inc;
    __syncthreads();
    if (threadIdx.x < 16) {
        const int s = wsum[threadIdx.x];
        int is = s;
#pragma unroll
        for (int dd = 1; dd < 16; dd <<= 1) {
            const int u = __shfl_up(is, dd);
            if (threadIdx.x >= dd) is += u;
        }
        wpre[threadIdx.x] = is - s;
    }
    __syncthreads();
    const int ex = (inc - d) + wpre[wid] + partials[blockIdx.x];
    if (i <= N_NODES) offsets[i] = ex;               // offsets[N_NODES] == E
    if (i < N_NODES) {
        cursor[i] = ex;
        dinv[i]   = rsqrtf((float)(d + 1));          // +1 self loop
    }
}

// ---- counting-sort fill: csr_src[pos] = src ----
__global__ void k_fill(const int* __restrict__ src, const int* __restrict__ dst, int E,
                       int* __restrict__ cursor, int* __restrict__ csr_src) {
    int i = blockIdx.x * blockDim.x + threadIdx.x;
    if (i < E) {
        const int d   = dst[i];
        const int pos = atomicAdd(&cursor[d], 1);
        csr_src[pos] = src[i];
    }
}

// ---- Hs(fp16) = dinv[row] * (X @ W) ----
// lane = column pair: X[row][k] wave-uniform -> scalar loads; W in LDS.
// Epilogue packs to half2: Hs row = 128 fp16 = 256 B.
__global__ __launch_bounds__(512) void k_gemm(const float* __restrict__ X,
                                              const float* __restrict__ W,
                                              const float* __restrict__ dinv,
                                              __half* __restrict__ Hs, int nrows) {
    __shared__ float2 Ws[F * 64];                    // Ws[k*64 + j] = W[k][2j..2j+1]
    const float2* Wv = (const float2*)W;
    for (int i = threadIdx.x; i < F * 64; i += 512) Ws[i] = Wv[i];
    __syncthreads();

    const int wid   = threadIdx.x >> 6;
    const int lane  = threadIdx.x & 63;
    const int ntile = nrows >> 3;                    // 8 rows per wave-tile
    __half2* __restrict__ Hv = (__half2*)Hs;

    int tile = __builtin_amdgcn_readfirstlane(blockIdx.x * 8 + wid);
    const int stride = gridDim.x * 8;
    for (; tile < ntile; tile += stride) {
        const int r0 = tile * 8;
        const float* __restrict__ Xr = X + r0 * F;
        float2 acc[8];
#pragma unroll
        for (int r = 0; r < 8; ++r) acc[r] = make_float2(0.f, 0.f);
#pragma unroll 8
        for (int k = 0; k < F; ++k) {
            const float2 w = Ws[k * 64 + lane];
#pragma unroll
            for (int r = 0; r < 8; ++r) {
                const float xv = Xr[r * F + k];
                acc[r].x = fmaf(xv, w.x, acc[r].x);
                acc[r].y = fmaf(xv, w.y, acc[r].y);
            }
        }
#pragma unroll
        for (int r = 0; r < 8; ++r) {
            const float dn = dinv[r0 + r];
            Hv[(r0 + r) * 64 + lane] =
                __float22half2_rn(make_float2(dn * acc[r].x, dn * acc[r].y));
        }
    }
}

// ---- node gather (fp16 rows, fp32 accumulate) ----
// one 32-lane group per node; lane reads 8 B (4 fp16) per edge; 4-deep unroll.
__global__ __launch_bounds__(256) void k_gather(const int* __restrict__ offsets,
                                                const int* __restrict__ csr_src,
                                                const __half* __restrict__ Hs,
                                                const float* __restrict__ dinv,
                                                const float* __restrict__ b,
                                                float* __restrict__ out) {
    const int tid = blockIdx.x * blockDim.x + threadIdx.x;
    const int g   = tid >> 5;                        // global 32-lane group
    const int l32 = threadIdx.x & 31;
    const int ng  = (gridDim.x * blockDim.x) >> 5;
    const uint2* __restrict__ Hv = (const uint2*)Hs; // row = 32 x uint2 (4 fp16 each)
    float4* __restrict__ outv = (float4*)out;
    const float4 bb = ((const float4*)b)[l32];
    for (int n = g; n < N_NODES; n += ng) {
        const int beg = offsets[n], end = offsets[n + 1];
        float4 a0 = make_float4(0.f, 0.f, 0.f, 0.f);
        float4 a1 = make_float4(0.f, 0.f, 0.f, 0.f);
        float4 a2 = make_float4(0.f, 0.f, 0.f, 0.f);
        float4 a3 = make_float4(0.f, 0.f, 0.f, 0.f);
        {   // self-loop message (pre-scaled)
            const uint2 raw = Hv[n * 32 + l32];
            const float2 f0 = __half22float2(*(const __half2*)&raw.x);
            const float2 f1 = __half22float2(*(const __half2*)&raw.y);
            a0.x += f0.x; a0.y += f0.y; a0.z += f1.x; a0.w += f1.y;
        }
        int e = beg;
        for (; e + 3 < end; e += 4) {
            const int s0 = csr_src[e];
            const int s1 = csr_src[e + 1];
            const int s2 = csr_src[e + 2];
            const int s3 = csr_src[e + 3];
            const uint2 r0 = Hv[s0 * 32 + l32];
            const uint2 r1 = Hv[s1 * 32 + l32];
            const uint2 r2 = Hv[s2 * 32 + l32];
            const uint2 r3 = Hv[s3 * 32 + l32];
            float2 f;
            f = __half22float2(*(const __half2*)&r0.x); a0.x += f.x; a0.y += f.y;
            f = __half22float2(*(const __half2*)&r0.y); a0.z += f.x; a0.w += f.y;
            f = __half22float2(*(const __half2*)&r1.x); a1.x += f.x; a1.y += f.y;
            f = __half22float2(*(const __half2*)&r1.y); a1.z += f.x; a1.w += f.y;
            f = __half22float2(*(const __half2*)&r2.x); a2.x += f.x; a2.y += f.y;
            f = __half22float2(*(const __half2*)&r2.y); a2.z += f.x; a2.w += f.y;
            f = __half22float2(*(const __half2*)&r3.x); a3.x += f.x; a3.y += f.y;
            f = __half22float2(*(const __half2*)&r3.y); a3.z += f.x; a3.w += f.y;
        }
        for (; e < end; ++e) {
            const uint2 r0 = Hv[csr_src[e] * 32 + l32];
            float2 f;
            f = __half22float2(*(const __half2*)&r0.x); a1.x += f.x; a1.y += f.y;
            f = __half22float2(*(const __half2*)&r0.y); a1.z += f.x; a1.w += f.y;
        }
        const float dn = dinv[n];
        float4 o;
        o.x = fmaxf(fmaf(dn, (a0.x + a1.x) + (a2.x + a3.x), bb.x), 0.f);
        o.y = fmaxf(fmaf(dn, (a0.y + a1.y) + (a2.y + a3.y), bb.y), 0.f);
        o.z = fmaxf(fmaf(dn, (a0.z + a1.z) + (a2.z + a3.z), bb.z), 0.f);
        o.w = fmaxf(fmaf(dn, (a0.w + a1.w) + (a2.w + a3.w), bb.w), 0.f);
        outv[n * 32 + l32] = o;
    }
}

extern "C" void kernel_launch(void* const* d_in, const int* in_sizes, int n_in,
                              void* d_out, int out_size, void* d_ws, size_t ws_size,
                              hipStream_t stream) {
    const float* x  = (const float*)d_in[0];
    const int*   ei = (const int*)  d_in[1];
    const float* W1 = (const float*)d_in[2];
    const float* b1 = (const float*)d_in[3];
    const float* W2 = (const float*)d_in[4];
    const float* b2 = (const float*)d_in[5];
    float* out = (float*)d_out;

    const int E = in_sizes[1] / 2;        // 800000
    const int* srcp = ei;                 // edge_index[0]
    const int* dstp = ei + E;             // edge_index[1]

    // ---- workspace carve-up (prefix = 1000004 ints -> Hs 16B-aligned) ----
    int*    deg      = (int*)d_ws;                 // 50000
    int*    offsets  = deg + N_NODES;              // 50004 (N+1 used, padded)
    int*    cursor   = offsets + N_NODES + 4;      // 50000
    int*    csr_src  = cursor + N_NODES;           // 800000
    float*  dinv     = (float*)(csr_src + E);      // 50000
    __half* Hs       = (__half*)(dinv + N_NODES);  // N*F fp16, 16B-aligned
    int*    partials = (int*)(Hs + N_NODES * F);   // SCAN_NB

    // ---- CSR build (shared by both layers) ----
    hipMemsetAsync(deg, 0, N_NODES * sizeof(int), stream);
    k_count  <<<(E + 255) / 256, 256, 0, stream>>>(dstp, E, deg);
    k_bsum   <<<SCAN_NB, SCAN_B, 0, stream>>>(deg, partials);
    k_pscan  <<<1, 64, 0, stream>>>(partials);
    k_offsets<<<SCAN_NB, SCAN_B, 0, stream>>>(deg, partials, offsets, cursor, dinv, E);
    k_fill   <<<(E + 255) / 256, 256, 0, stream>>>(srcp, dstp, E, cursor, csr_src);

    const int gemm_blocks = (N_NODES / 8 + 7) / 8;   // 782

    // ---- layer 1 ----
    k_gemm  <<<gemm_blocks, 512, 0, stream>>>(x, W1, dinv, Hs, N_NODES);
    k_gather<<<2048, 256, 0, stream>>>(offsets, csr_src, Hs, dinv, b1, out);

    // ---- layer 2 ----
    k_gemm  <<<gemm_blocks, 512, 0, stream>>>(out, W2, dinv, Hs, N_NODES);
    k_gather<<<2048, 256, 0, stream>>>(offsets, csr_src, Hs, dinv, b2, out);
}